// Round 1
// baseline (444.328 us; speedup 1.0000x reference)
//
#include <hip/hip_runtime.h>
#include <cstdint>

// Problem constants
#define TOKENS 8192
#define DIM 4096
#define D4 (DIM / 4)            // 1024 float4 per row
#define NEXP 8
#define TOPK 2
#define SLOTS (TOKENS * TOPK)   // 16384

// Fused-kernel geometry
#define NBLK 512                // 2 blocks/CU on 256 CUs -> all co-resident
#define TPB 256                 // 4 waves
#define TOK_PER_BLK 16          // 4 waves * 4 tokens
#define CH 32                   // slots per block == chunk size
// NCHUNK == NBLK == 512

// Output layout (all fp32, concatenated in reference return order)
#define OUT_CNT ((size_t)SLOTS * DIM)       // 67108864
#define OUT_SCAT (OUT_CNT + NEXP)           // 67108872
#define OUT_SCORE (OUT_SCAT + SLOTS)        // 67125256

// Native clang vector (required by __builtin_nontemporal_store)
typedef float vfloat4 __attribute__((ext_vector_type(4)));

// ---------------------------------------------------------------------------
// ONE persistent kernel: score -> (grid bar) -> scan by block 0 -> (grid bar)
// -> rank+scatter-meta -> gather. eid/prob/pos live in LDS; only the 512x8
// chunk histogram crosses blocks. Grid barriers: two monotonic device-scope
// counters (bar[0] for phase-1 arrival, bar[32] for scan-done), reset by a
// hipMemsetAsync each launch. __launch_bounds__(256,2) caps VGPR at 256 so
// 2 blocks/CU are guaranteed resident -> no deadlock.
// ---------------------------------------------------------------------------
__global__ __launch_bounds__(TPB, 2) void k_moe(const float* __restrict__ x,
                                                const float* __restrict__ W,
                                                int* __restrict__ hist,
                                                int* __restrict__ bar,
                                                float* __restrict__ out)
{
    __shared__ int   s_eid[CH];
    __shared__ float s_prob[CH];
    __shared__ int   s_cnt[NEXP];
    __shared__ int   s_pos[CH];

    const int wave = threadIdx.x >> 6;
    const int lane = threadIdx.x & 63;
    const int blk  = blockIdx.x;
    const int tok0 = (blk * 4 + wave) * 4;

    if (threadIdx.x < NEXP) s_cnt[threadIdx.x] = 0;
    __syncthreads();

    // ---- phase 1: score (bit-identical arithmetic to the 389us version) ----
    const float4* x4 = reinterpret_cast<const float4*>(x);
    const float4* W4 = reinterpret_cast<const float4*>(W);

    float acc[4][NEXP];
#pragma unroll
    for (int t = 0; t < 4; ++t)
#pragma unroll
        for (int e = 0; e < NEXP; ++e) acc[t][e] = 0.f;

    for (int i = 0; i < 16; ++i) {
        const int d4 = lane + 64 * i;
        float4 xv[4];
#pragma unroll
        for (int t = 0; t < 4; ++t) xv[t] = x4[(size_t)(tok0 + t) * D4 + d4];
#pragma unroll
        for (int e = 0; e < NEXP; ++e) {
            const float4 w = W4[e * D4 + d4];
#pragma unroll
            for (int t = 0; t < 4; ++t) {
                acc[t][e] = fmaf(xv[t].x, w.x, acc[t][e]);
                acc[t][e] = fmaf(xv[t].y, w.y, acc[t][e]);
                acc[t][e] = fmaf(xv[t].z, w.z, acc[t][e]);
                acc[t][e] = fmaf(xv[t].w, w.w, acc[t][e]);
            }
        }
    }

#pragma unroll
    for (int t = 0; t < 4; ++t)
#pragma unroll
        for (int e = 0; e < NEXP; ++e) {
            float v = acc[t][e];
#pragma unroll
            for (int off = 32; off >= 1; off >>= 1) v += __shfl_xor(v, off);
            acc[t][e] = v;
        }

    // Top-2 + softmax; redundant on all lanes, lane t publishes token t to LDS.
#pragma unroll
    for (int t = 0; t < 4; ++t) {
        int i0 = 0;
        float m0 = acc[t][0];
#pragma unroll
        for (int e = 1; e < NEXP; ++e)
            if (acc[t][e] > m0) { m0 = acc[t][e]; i0 = e; }  // strict > keeps lowest idx
        int i1 = -1;
        float m1 = -INFINITY;
#pragma unroll
        for (int e = 0; e < NEXP; ++e)
            if (e != i0 && acc[t][e] > m1) { m1 = acc[t][e]; i1 = e; }
        const float z = __expf(m1 - m0);   // <= 1
        const float inv = 1.0f / (1.0f + z);
        if (lane == t) {
            const int ls = (wave * 4 + t) * 2;   // local slot in this block's chunk
            s_eid[ls]      = i0;
            s_eid[ls + 1]  = i1;
            s_prob[ls]     = inv;
            s_prob[ls + 1] = z * inv;
            atomicAdd(&s_cnt[i0], 1);
            atomicAdd(&s_cnt[i1], 1);
        }
    }
    __syncthreads();
    if (threadIdx.x < NEXP) hist[blk * NEXP + threadIdx.x] = s_cnt[threadIdx.x];

    // ---- grid barrier 1 (arrive) ----
    __syncthreads();   // drains vmcnt: hist stores are in L2 before the fence
    if (threadIdx.x == 0) { __threadfence(); atomicAdd(&bar[0], 1); }

    // ---- block 0: exclusive scan of 512 chunks x 8 experts -> bases ----
    if (blk == 0) {
        if (threadIdx.x == 0) {
            while (__hip_atomic_load(&bar[0], __ATOMIC_ACQUIRE,
                                     __HIP_MEMORY_SCOPE_AGENT) < NBLK)
                __builtin_amdgcn_s_sleep(2);
        }
        __syncthreads();           // lanes 1..255 see invalidated L1 view
        if (threadIdx.x < 64) {
            int v[NEXP][8];
#pragma unroll
            for (int q = 0; q < NEXP; ++q)
#pragma unroll
                for (int r = 0; r < 8; ++r)
                    v[q][r] = hist[(r * 64 + lane) * NEXP + q];  // all 64 loads in flight
            int base = 0;
#pragma unroll
            for (int q = 0; q < NEXP; ++q) {
                int run = 0;
#pragma unroll
                for (int r = 0; r < 8; ++r) {
                    int incl = v[q][r];
#pragma unroll
                    for (int off = 1; off <= 32; off <<= 1) {
                        const int n = __shfl_up(incl, off);
                        if (lane >= off) incl += n;
                    }
                    hist[(r * 64 + lane) * NEXP + q] = base + run + incl - v[q][r];
                    run += __shfl(incl, 63);   // uniform
                }
                if (lane == 0) out[OUT_CNT + q] = (float)run;
                base += run;
            }
        }
    }

    // ---- grid barrier 2 (arrive + wait) ----
    __syncthreads();   // block 0: drain scan stores before the fence
    if (threadIdx.x == 0) {
        __threadfence();
        atomicAdd(&bar[32], 1);    // separate cache line from bar[0]
        while (__hip_atomic_load(&bar[32], __ATOMIC_ACQUIRE,
                                 __HIP_MEMORY_SCOPE_AGENT) < NBLK)
            __builtin_amdgcn_s_sleep(2);
    }
    __syncthreads();

    // ---- phase 3: rank own chunk, emit scatter_indices / scores_sorted ----
    if (threadIdx.x < 64) {
        const int e = (lane < CH) ? s_eid[lane] : -1;
        const unsigned long long lt = (1ull << lane) - 1ull;
        int rank = 0;
#pragma unroll
        for (int q = 0; q < NEXP; ++q) {
            const unsigned long long m = __ballot(e == q);
            if (e == q) rank = __popcll(m & lt);
        }
        if (lane < CH) {
            const int p = hist[blk * NEXP + e] + rank;
            s_pos[lane] = p;
            const int s = blk * CH + lane;          // global slot id
            out[OUT_SCAT + p]  = (float)(s >> 1);   // token id
            out[OUT_SCORE + p] = s_prob[lane];
        }
    }
    __syncthreads();

    // ---- phase 4: gather. Read own 16 x rows (L3-warm), NT-store to both
    // destination rows (keep x resident in L3). ----
    const vfloat4* xx = reinterpret_cast<const vfloat4*>(x) +
                        (size_t)(blk * TOK_PER_BLK) * D4;
    vfloat4* o4 = reinterpret_cast<vfloat4*>(out);
#pragma unroll 2
    for (int tt = 0; tt < TOK_PER_BLK; ++tt) {
        const int p0 = s_pos[2 * tt];
        const int p1 = s_pos[2 * tt + 1];
        const vfloat4* src = xx + (size_t)tt * D4;
        vfloat4* d0 = o4 + (size_t)p0 * D4;
        vfloat4* d1 = o4 + (size_t)p1 * D4;
#pragma unroll
        for (int i = 0; i < 4; ++i) {
            const int idx = threadIdx.x + TPB * i;
            const vfloat4 v = src[idx];
            __builtin_nontemporal_store(v, d0 + idx);
            __builtin_nontemporal_store(v, d1 + idx);
        }
    }
}

extern "C" void kernel_launch(void* const* d_in, const int* in_sizes, int n_in,
                              void* d_out, int out_size, void* d_ws, size_t ws_size,
                              hipStream_t stream)
{
    const float* x = (const float*)d_in[0];
    const float* W = (const float*)d_in[1];
    float* out = (float*)d_out;

    // Workspace: hist[512*8] int at +0 | barrier counters at +64KB (bar[0], bar[32])
    int* hist = (int*)d_ws;
    int* bar  = (int*)((char*)d_ws + 64 * 1024);

    hipMemsetAsync(bar, 0, 256, stream);   // reset both barrier counters (capture-safe)
    k_moe<<<NBLK, TPB, 0, stream>>>(x, W, hist, bar, out);
}